// Round 17
// baseline (302.607 us; speedup 1.0000x reference)
//
#include <hip/hip_runtime.h>
#include <hip/hip_bf16.h>
#include <stdint.h>

#define S_LEN 2048
#define NB 2
#define NH 16
#define DM 1024
#define KDIM 64
#define MTOK (NB*S_LEN)   // 4096 tokens

typedef __attribute__((ext_vector_type(8))) short bf16x8;
typedef __attribute__((ext_vector_type(4))) float f32x4;
typedef __attribute__((ext_vector_type(4))) unsigned short u16x4;
typedef __attribute__((ext_vector_type(8))) unsigned short u16x8;

#define AS1 __attribute__((address_space(1)))
#define AS3 __attribute__((address_space(3)))

__device__ __forceinline__ unsigned short f2bf(float f) {
  unsigned int u = __builtin_bit_cast(unsigned int, f);
  return (unsigned short)((u + 0x7fffu + ((u >> 16) & 1u)) >> 16);   // RNE
}
__device__ __forceinline__ f32x4 mfma16(bf16x8 a, bf16x8 b, f32x4 c) {
  return __builtin_amdgcn_mfma_f32_16x16x32_bf16(a, b, c, 0, 0, 0);
}

// ---------------------------------------------------------------------------
// fp32 -> bf16 convert: only the 4 weight matrices
// ---------------------------------------------------------------------------
struct CvtArgs {
  const float* src[4];
  unsigned short* dst[4];
  int n[4];
};

__global__ __launch_bounds__(256) void cvt_f32_bf16(CvtArgs a) {
  const int seg = blockIdx.y;
  const float* __restrict__ s = a.src[seg];
  unsigned short* __restrict__ d = a.dst[seg];
  const int n4 = a.n[seg] >> 2;
  const int stride = gridDim.x * blockDim.x;
  for (int i = blockIdx.x * blockDim.x + threadIdx.x; i < n4; i += stride) {
    const float4 v = reinterpret_cast<const float4*>(s)[i];
    u16x4 o;
    o[0] = f2bf(v.x); o[1] = f2bf(v.y); o[2] = f2bf(v.z); o[3] = f2bf(v.w);
    reinterpret_cast<u16x4*>(d)[i] = o;
  }
}

// ---------------------------------------------------------------------------
// gemm_cvt v2 (R16-proven): QKV projections with fused fp32->bf16 A-convert,
// counted-vmcnt ledger.
// ---------------------------------------------------------------------------
struct GemmCvtArgs {
  const float* A[3];
  const unsigned short* W[3];
  const float* bias[3];
  void* dst[3];
  int mode[3];
};

__global__ __launch_bounds__(256, 2)
void gemm_cvt(GemmCvtArgs ga)
{
  __shared__ __align__(16) char smem[32768];   // 2 x (A 8K + B 8K); Cs union

  const int z = blockIdx.z;
  const float* __restrict__ Af = ga.A[z];
  const unsigned short* __restrict__ Bw = ga.W[z];
  const float* __restrict__ bias = ga.bias[z];
  void* __restrict__ dst = ga.dst[z];
  const int mode = ga.mode[z];

  const int t = threadIdx.x;
  const int w = t >> 6, l = t & 63;
  const int g = l >> 4, cl = l & 15;

  const int L   = blockIdx.x + 8 * blockIdx.y;   // 0..255
  const int xcd = L & 7, ix = L >> 3;
  const int m0  = (xcd * 4 + (ix & 3)) * 128;
  const int n0  = (ix >> 2) * 128;

  const float* Ap = Af + (size_t)(m0 + (t >> 2)) * DM + (t & 3) * 8;
  const unsigned short* Bg = Bw + (size_t)(n0 + (t >> 2)) * DM + (t & 3) * 8;

  const int wm = (w >> 1) * 64, wn = (w & 1) * 64;

  f32x4 acc[4][4];
  #pragma unroll
  for (int i = 0; i < 4; ++i)
    #pragma unroll
    for (int j = 0; j < 4; ++j) acc[i][j] = 0.f;

  #define STAGE_B(step) do {                                                        \
    AS3 char* _buf = (AS3 char*)smem + ((step) & 1) * 16384;                         \
    __builtin_amdgcn_global_load_lds((const AS1 void*)(Bg + (step)*32),              \
                                     (AS3 void*)(_buf + 8192 + w*1024),   16, 0, 0); \
    __builtin_amdgcn_global_load_lds((const AS1 void*)(Bg + (step)*32 + 64*DM),      \
                                     (AS3 void*)(_buf + 12288 + w*1024),  16, 0, 0); \
  } while (0)

  #define ALOAD(step, ra, rb, rc, rd) do {                                           \
    const float* _p = Ap + (step) * 32;                                              \
    ra = *reinterpret_cast<const float4*>(_p);                                       \
    rb = *reinterpret_cast<const float4*>(_p + 4);                                   \
    const float* _q = _p + (size_t)64 * DM;                                          \
    rc = *reinterpret_cast<const float4*>(_q);                                       \
    rd = *reinterpret_cast<const float4*>(_q + 4);                                   \
  } while (0)

  #define AWRITE(step, ra, rb, rc, rd) do {                                          \
    AS3 char* _buf = (AS3 char*)smem + ((step) & 1) * 16384;                         \
    u16x8 _w0, _w1;                                                                  \
    _w0[0]=f2bf(ra.x); _w0[1]=f2bf(ra.y); _w0[2]=f2bf(ra.z); _w0[3]=f2bf(ra.w);      \
    _w0[4]=f2bf(rb.x); _w0[5]=f2bf(rb.y); _w0[6]=f2bf(rb.z); _w0[7]=f2bf(rb.w);      \
    _w1[0]=f2bf(rc.x); _w1[1]=f2bf(rc.y); _w1[2]=f2bf(rc.z); _w1[3]=f2bf(rc.w);      \
    _w1[4]=f2bf(rd.x); _w1[5]=f2bf(rd.y); _w1[6]=f2bf(rd.z); _w1[7]=f2bf(rd.w);      \
    *(AS3 u16x8*)(_buf + t*16) = _w0;                                                \
    *(AS3 u16x8*)(_buf + 4096 + t*16) = _w1;                                         \
  } while (0)

  #define COMPUTE(s) do {                                                            \
    const AS3 unsigned short* bufA =                                                 \
        (const AS3 unsigned short*)((AS3 char*)smem + ((s) & 1) * 16384);            \
    const AS3 unsigned short* bufB = bufA + 4096;                                    \
    bf16x8 af[4], bfv[4];                                                            \
    _Pragma("unroll")                                                                \
    for (int i = 0; i < 4; ++i)                                                      \
      af[i] = *(const AS3 bf16x8*)(bufA + (wm + 16*i + cl) * 32 + g*8);              \
    _Pragma("unroll")                                                                \
    for (int j = 0; j < 4; ++j)                                                      \
      bfv[j] = *(const AS3 bf16x8*)(bufB + (wn + 16*j + cl) * 32 + g*8);             \
    _Pragma("unroll")                                                                \
    for (int i = 0; i < 4; ++i)                                                      \
      _Pragma("unroll")                                                              \
      for (int j = 0; j < 4; ++j)                                                    \
        acc[i][j] = mfma16(af[i], bfv[j], acc[i][j]);                                \
  } while (0)

  #define GSEC(s, c0,c1,c2,c3, n0_,n1_,n2_,n3_) do {                                 \
    asm volatile("s_waitcnt lgkmcnt(0)" ::: "memory");                               \
    asm volatile("s_waitcnt vmcnt(4)" ::: "memory");   /* B(s) landed */             \
    __builtin_amdgcn_s_barrier();                                                    \
    __builtin_amdgcn_sched_barrier(0);                                               \
    STAGE_B((s) + 1);                                                                \
    COMPUTE(s);                                                                      \
    asm volatile("s_waitcnt vmcnt(2)" ::: "memory");   /* A(s+1) landed */           \
    AWRITE((s) + 1, c0, c1, c2, c3);                                                 \
    if ((s) + 2 < 32) ALOAD((s) + 2, n0_, n1_, n2_, n3_);                            \
  } while (0)

  float4 e0, e1, e2, e3, o0, o1, o2, o3;
  STAGE_B(0);
  ALOAD(0, e0, e1, e2, e3);
  ALOAD(1, o0, o1, o2, o3);
  asm volatile("s_waitcnt vmcnt(4)" ::: "memory");   // B(0) + A(0) landed
  AWRITE(0, e0, e1, e2, e3);

  for (int sp = 0; sp < 15; ++sp) {
    GSEC(2*sp,     o0, o1, o2, o3,  e0, e1, e2, e3);
    GSEC(2*sp + 1, e0, e1, e2, e3,  o0, o1, o2, o3);
  }
  GSEC(30, o0, o1, o2, o3,  e0, e1, e2, e3);
  asm volatile("s_waitcnt lgkmcnt(0)" ::: "memory");
  asm volatile("s_waitcnt vmcnt(0)" ::: "memory");
  __builtin_amdgcn_s_barrier();
  __builtin_amdgcn_sched_barrier(0);
  COMPUTE(31);
  #undef GSEC
  #undef COMPUTE
  #undef AWRITE
  #undef ALOAD
  #undef STAGE_B

  if (mode == 1) {
    unsigned short* Cs = (unsigned short*)smem;
    __syncthreads();
    #pragma unroll
    for (int i = 0; i < 4; ++i) {
      #pragma unroll
      for (int j = 0; j < 4; ++j) {
        const int n = wn + 16*j + cl;
        const float bn = bias[n0 + n];
        const int u = (wm >> 2) + 4*i + g;
        const int us = u ^ (n & 31);
        u16x4 o;
        #pragma unroll
        for (int r = 0; r < 4; ++r) o[r] = f2bf(acc[i][j][r] + bn);
        *reinterpret_cast<u16x4*>(&Cs[n*128 + us*4]) = o;
      }
    }
    __syncthreads();
    {
      const int n = t >> 1, mh = (t & 1) * 64;
      const int ncol = n0 + n;
      const int h = ncol >> 6, d = ncol & (KDIM-1);
      const int b = m0 >> 11, s0 = m0 & (S_LEN-1);
      unsigned short* drow = (unsigned short*)dst
          + ((size_t)(b*NH + h)*KDIM + d)*S_LEN + s0 + mh;
      #pragma unroll
      for (int mm = 0; mm < 4; ++mm) {
        u16x4 v[4];
        #pragma unroll
        for (int k = 0; k < 4; ++k) {
          const int us = ((mh >> 2) + mm*4 + k) ^ (n & 31);
          v[k] = *reinterpret_cast<const u16x4*>(&Cs[n*128 + us*4]);
        }
        u16x8 w01, w23;
        #pragma unroll
        for (int e = 0; e < 4; ++e) {
          w01[e] = v[0][e]; w01[4+e] = v[1][e];
          w23[e] = v[2][e]; w23[4+e] = v[3][e];
        }
        *reinterpret_cast<u16x8*>(drow + mm*16)     = w01;
        *reinterpret_cast<u16x8*>(drow + mm*16 + 8) = w23;
      }
    }
  } else {
    #pragma unroll
    for (int i = 0; i < 4; ++i)
      #pragma unroll
      for (int j = 0; j < 4; ++j) {
        const int ncol = n0 + wn + 16*j + cl;
        const float bn = bias[ncol];
        #pragma unroll
        for (int r = 0; r < 4; ++r) {
          const int m = m0 + wm + 16*i + g*4 + r;
          const float v = acc[i][j][r] + bn;
          const int b = m >> 11, sR = m & (S_LEN-1);
          const int h = ncol >> 6, d = ncol & (KDIM-1);
          ((unsigned short*)dst)[((size_t)(b*NH + h)*S_LEN + sR)*KDIM + d] = f2bf(v);
        }
      }
  }
}

// ---------------------------------------------------------------------------
// Pipelined GEMM (R9-proven) for the out-projection.
// ---------------------------------------------------------------------------
__global__ __launch_bounds__(256, 2)
void gemm_pipe(const unsigned short* __restrict__ A,
               const unsigned short* __restrict__ Bw,
               const float* __restrict__ bias,
               float* __restrict__ dst)
{
  __shared__ __align__(16) char smem[32768];

  const int t = threadIdx.x;
  const int w = t >> 6, l = t & 63;
  const int g = l >> 4, cl = l & 15;

  const int L   = blockIdx.x + 8 * blockIdx.y;   // 0..255
  const int xcd = L & 7, ix = L >> 3;
  const int m0  = (xcd * 4 + (ix & 3)) * 128;
  const int n0  = (ix >> 2) * 128;

  const unsigned short* Ag = A  + (size_t)(m0 + (t >> 2)) * DM + (t & 3) * 8;
  const unsigned short* Bg = Bw + (size_t)(n0 + (t >> 2)) * DM + (t & 3) * 8;

  const int wm = (w >> 1) * 64, wn = (w & 1) * 64;

  f32x4 acc[4][4];
  #pragma unroll
  for (int i = 0; i < 4; ++i)
    #pragma unroll
    for (int j = 0; j < 4; ++j) acc[i][j] = 0.f;

  #define STAGE(step) do {                                                          \
    AS3 char* _buf = (AS3 char*)smem + ((step) & 1) * 16384;                         \
    __builtin_amdgcn_global_load_lds((const AS1 void*)(Ag + (step)*32),              \
                                     (AS3 void*)(_buf + w*1024),          16, 0, 0); \
    __builtin_amdgcn_global_load_lds((const AS1 void*)(Ag + (step)*32 + 64*DM),      \
                                     (AS3 void*)(_buf + 4096 + w*1024),   16, 0, 0); \
    __builtin_amdgcn_global_load_lds((const AS1 void*)(Bg + (step)*32),              \
                                     (AS3 void*)(_buf + 8192 + w*1024),   16, 0, 0); \
    __builtin_amdgcn_global_load_lds((const AS1 void*)(Bg + (step)*32 + 64*DM),      \
                                     (AS3 void*)(_buf + 12288 + w*1024),  16, 0, 0); \
  } while (0)

  STAGE(0);
  for (int s = 0; s < 32; ++s) {
    if (s < 31) {
      STAGE(s + 1);
      asm volatile("s_waitcnt vmcnt(4)" ::: "memory");
    } else {
      asm volatile("s_waitcnt vmcnt(0)" ::: "memory");
    }
    __builtin_amdgcn_s_barrier();
    __builtin_amdgcn_sched_barrier(0);

    const AS3 unsigned short* bufA =
        (const AS3 unsigned short*)((AS3 char*)smem + (s & 1) * 16384);
    const AS3 unsigned short* bufB = bufA + 4096;
    bf16x8 af[4], bfv[4];
    #pragma unroll
    for (int i = 0; i < 4; ++i)
      af[i] = *(const AS3 bf16x8*)(bufA + (wm + 16*i + cl) * 32 + g*8);
    #pragma unroll
    for (int j = 0; j < 4; ++j)
      bfv[j] = *(const AS3 bf16x8*)(bufB + (wn + 16*j + cl) * 32 + g*8);
    #pragma unroll
    for (int i = 0; i < 4; ++i)
      #pragma unroll
      for (int j = 0; j < 4; ++j)
        acc[i][j] = mfma16(af[i], bfv[j], acc[i][j]);

    __builtin_amdgcn_sched_barrier(0);
    __builtin_amdgcn_s_barrier();
  }
  #undef STAGE

  #pragma unroll
  for (int i = 0; i < 4; ++i)
    #pragma unroll
    for (int j = 0; j < 4; ++j) {
      const int ncol = n0 + wn + 16*j + cl;
      const float bn = bias[ncol];
      #pragma unroll
      for (int r = 0; r < 4; ++r) {
        const int m = m0 + wm + 16*i + g*4 + r;
        dst[(size_t)m * DM + ncol] = acc[i][j][r] + bn;
      }
    }
}

// ---------------------------------------------------------------------------
// Fused attention v12: per block TWO q-tiles (t0,t1) of the same head.
// Phase A0 = sums(t0); phase AB = store+PV(t0) MERGED with sums(t1) sharing
// the staged K chunks; phase B1 = store+PV(t1). Sections: 96 per 2 tiles
// (vs 128) and the store stream runs during 2/3 of the kernel.
// Ledgers per phase identical to R14-proven: A vmcnt(4); B/AB vmcnt(16).
// Grid 256 (1 block/CU), launch_bounds(512,2) for register headroom.
// ---------------------------------------------------------------------------
__global__ __launch_bounds__(512, 2)
void attn_fused12(const unsigned short* __restrict__ Qh,
                  const unsigned short* __restrict__ Kh,
                  const unsigned short* __restrict__ Vt,
                  float* __restrict__ attn,
                  unsigned short* __restrict__ ctx)
{
  __shared__ __align__(16) char smem[75776];
  AS3 char* const KB = (AS3 char*)smem;
  AS3 char* const VB = (AS3 char*)smem + 32768;

  const int id  = blockIdx.x;                 // 256 = 8 XCD x 32
  const int swz = (id & 7) * 32 + (id >> 3);  // bijective XCD swizzle
  const int bh  = swz >> 3;                   // head 0..31
  const int q0  = (swz & 7) * 256;            // 256-row pair base (t0, t1=+128)

  const int t = threadIdx.x, w = t >> 6, l = t & 63;
  const int g = l >> 4, cl = l & 15;
  AS3 char* const PBw = (AS3 char*)smem + 65536 + w * 1280;
  const int b = bh >> 4, h = bh & 15;

  const unsigned short* QbA = Qh + ((size_t)bh * S_LEN + q0 + w*16 + cl) * KDIM;
  const bf16x8 qA0 = *reinterpret_cast<const bf16x8*>(QbA + g*8);
  const bf16x8 qA1 = *reinterpret_cast<const bf16x8*>(QbA + 32 + g*8);
  const unsigned short* QbB = QbA + (size_t)128 * KDIM;
  const bf16x8 qB0 = *reinterpret_cast<const bf16x8*>(QbB + g*8);
  const bf16x8 qB1 = *reinterpret_cast<const bf16x8*>(QbB + 32 + g*8);

  const int rs = (w & 3)*8 + (l >> 3), js = l & 7;
  const unsigned short* pK = Kh + (size_t)bh*S_LEN*KDIM + (size_t)rs*KDIM
                                + (size_t)((js ^ (rs & 7)) * 8);
  const int dsv = (w & 3)*16 + (l >> 2), jv = l & 3;
  const int kst = (dsv & 3) ^ ((dsv >> 2) & 3);
  const unsigned short* pV = Vt + (size_t)bh*KDIM*S_LEN + (size_t)dsv*S_LEN
                                + (size_t)((jv ^ kst) * 8);

  const unsigned kvkey = (unsigned)((cl & 3) ^ ((cl >> 2) & 3));
  const unsigned koff0 = (unsigned)(cl*128 + ((g ^ (cl & 7)) << 4));
  const unsigned koff1 = (unsigned)(cl*128 + (((g + 4) ^ (cl & 7)) << 4));
  const float SC2 = 0.125f * 1.44269504f;     // 1/sqrt(64) * log2(e)

  #define STAGE_K(ch) do { int _b = (ch) & 7;                                               \
    if (w < 4) __builtin_amdgcn_global_load_lds((const AS1 void*)(pK + (size_t)(ch)*2048),  \
                   (AS3 void*)(KB + _b*4096 + (w&3)*1024), 16, 0, 0); } while (0)
  #define STAGE_KV(ch) do { int _b = (ch) & 7;                                              \
    if (w < 4) __builtin_amdgcn_global_load_lds((const AS1 void*)(pK + (size_t)(ch)*2048),  \
                   (AS3 void*)(KB + _b*4096 + (w&3)*1024), 16, 0, 0);                       \
    else       __builtin_amdgcn_global_load_lds((const AS1 void*)(pV + (size_t)(ch)*32),    \
                   (AS3 void*)(VB + _b*4096 + (w&3)*1024), 16, 0, 0); } while (0)

  // ================= PHASE A0: sums(t0), 32 sections x 64 kv ===============
  float sa0 = 0.f, sa1 = 0.f, sa2 = 0.f, sa3 = 0.f;

  for (int i = 0; i < 6; ++i) STAGE_K(i);
  for (int k = 0; k < 32; ++k) {
    const int c = 2 * k;
    if (w < 4) asm volatile("s_waitcnt vmcnt(4)" ::: "memory");
    __builtin_amdgcn_s_barrier();
    __builtin_amdgcn_sched_barrier(0);
    STAGE_K(c + 6);
    STAGE_K(c + 7);
    #pragma unroll
    for (int cc = 0; cc < 2; ++cc) {
      AS3 const char* kb = KB + ((c + cc) & 7) * 4096;
      #pragma unroll
      for (int s = 0; s < 2; ++s) {
        const bf16x8 k0 = *(const AS3 bf16x8*)(kb + s*2048 + koff0);
        const bf16x8 k1 = *(const AS3 bf16x8*)(kb + s*2048 + koff1);
        f32x4 acc = {0.f, 0.f, 0.f, 0.f};
        acc = mfma16(k0, qA0, acc);
        acc = mfma16(k1, qA1, acc);
        sa0 += __builtin_exp2f(acc[0] * SC2);
        sa1 += __builtin_exp2f(acc[1] * SC2);
        sa2 += __builtin_exp2f(acc[2] * SC2);
        sa3 += __builtin_exp2f(acc[3] * SC2);
      }
    }
  }

  float ssum = (sa0 + sa1) + (sa2 + sa3);
  ssum += __shfl_xor(ssum, 16, 64);
  ssum += __shfl_xor(ssum, 32, 64);
  const float inv0 = 1.0f / ssum;                // t0 row q = w*16 + cl

  __syncthreads();                               // drain phase A0

  // ========== PHASE AB: store+PV(t0) + sums(t1), 32 sections ===============
  float* const arow0 = attn + ((size_t)bh * S_LEN + q0 + w*16 + cl) * S_LEN + g*4;
  f32x4 accP[4];
  #pragma unroll
  for (int dt = 0; dt < 4; ++dt) accP[dt] = 0.f;
  float sb0 = 0.f, sb1 = 0.f, sb2 = 0.f, sb3 = 0.f;

  for (int i = 0; i < 6; ++i) STAGE_KV(i);
  for (int k = 0; k < 32; ++k) {
    const int c = 2 * k;
    if (k < 3) asm volatile("s_waitcnt vmcnt(4)"  ::: "memory");
    else       asm volatile("s_waitcnt vmcnt(16)" ::: "memory");
    __builtin_amdgcn_s_barrier();
    __builtin_amdgcn_sched_barrier(0);
    STAGE_KV(c + 6);
    STAGE_KV(c + 7);
    #pragma unroll
    for (int cc = 0; cc < 2; ++cc) {
      const int ch = c + cc;
      AS3 const char* kb = KB + (ch & 7) * 4096;
      AS3 const char* vb = VB + (ch & 7) * 4096;
      #pragma unroll
      for (int s = 0; s < 2; ++s) {
        const bf16x8 k0 = *(const AS3 bf16x8*)(kb + s*2048 + koff0);
        const bf16x8 k1 = *(const AS3 bf16x8*)(kb + s*2048 + koff1);
        f32x4 acc = {0.f, 0.f, 0.f, 0.f};
        acc = mfma16(k0, qA0, acc);
        acc = mfma16(k1, qA1, acc);
        f32x4 p;
        p[0] = __builtin_exp2f(acc[0] * SC2) * inv0;
        p[1] = __builtin_exp2f(acc[1] * SC2) * inv0;
        p[2] = __builtin_exp2f(acc[2] * SC2) * inv0;
        p[3] = __builtin_exp2f(acc[3] * SC2) * inv0;
        *reinterpret_cast<f32x4*>(arow0 + ch*32 + s*16) = p;
        u16x4 pb;
        pb[0] = f2bf(p[0]); pb[1] = f2bf(p[1]); pb[2] = f2bf(p[2]); pb[3] = f2bf(p[3]);
        *(AS3 u16x4*)(PBw + cl*80 + s*32 + g*8) = pb;
        // t1 sums on the SAME staged K fragments:
        f32x4 acc1 = {0.f, 0.f, 0.f, 0.f};
        acc1 = mfma16(k0, qB0, acc1);
        acc1 = mfma16(k1, qB1, acc1);
        sb0 += __builtin_exp2f(acc1[0] * SC2);
        sb1 += __builtin_exp2f(acc1[1] * SC2);
        sb2 += __builtin_exp2f(acc1[2] * SC2);
        sb3 += __builtin_exp2f(acc1[3] * SC2);
      }
      const bf16x8 ap = *(const AS3 bf16x8*)(PBw + cl*80 + g*16);
      #pragma unroll
      for (int dt = 0; dt < 4; ++dt) {
        const bf16x8 bv = *(const AS3 bf16x8*)(vb + (dt*16 + cl)*64 + ((g ^ kvkey) << 4));
        accP[dt] = mfma16(ap, bv, accP[dt]);
      }
    }
  }

  // t0 ctx write (normalized P -> O already normalized)
  #pragma unroll
  for (int r = 0; r < 4; ++r) {
    const size_t row = (size_t)(b * S_LEN + q0 + w*16 + g*4 + r);
    #pragma unroll
    for (int dt = 0; dt < 4; ++dt)
      ctx[row * DM + h * KDIM + dt*16 + cl] = f2bf(accP[dt][r]);
  }

  float ssum1 = (sb0 + sb1) + (sb2 + sb3);
  ssum1 += __shfl_xor(ssum1, 16, 64);
  ssum1 += __shfl_xor(ssum1, 32, 64);
  const float inv1 = 1.0f / ssum1;               // t1 row q = 128 + w*16 + cl

  __syncthreads();                               // drain phase AB

  // ================= PHASE B1: store+PV(t1), 32 sections ===================
  float* const arow1 = attn + ((size_t)bh * S_LEN + q0 + 128 + w*16 + cl) * S_LEN + g*4;
  #pragma unroll
  for (int dt = 0; dt < 4; ++dt) accP[dt] = 0.f;

  for (int i = 0; i < 6; ++i) STAGE_KV(i);
  for (int k = 0; k < 32; ++k) {
    const int c = 2 * k;
    if (k < 3) asm volatile("s_waitcnt vmcnt(4)"  ::: "memory");
    else       asm volatile("s_waitcnt vmcnt(16)" ::: "memory");
    __builtin_amdgcn_s_barrier();
    __builtin_amdgcn_sched_barrier(0);
    STAGE_KV(c + 6);
    STAGE_KV(c + 7);
    #pragma unroll
    for (int cc = 0; cc < 2; ++cc) {
      const int ch = c + cc;
      AS3 const char* kb = KB + (ch & 7) * 4096;
      AS3 const char* vb = VB + (ch & 7) * 4096;
      #pragma unroll
      for (int s = 0; s < 2; ++s) {
        const bf16x8 k0 = *(const AS3 bf16x8*)(kb + s*2048 + koff0);
        const bf16x8 k1 = *(const AS3 bf16x8*)(kb + s*2048 + koff1);
        f32x4 acc = {0.f, 0.f, 0.f, 0.f};
        acc = mfma16(k0, qB0, acc);
        acc = mfma16(k1, qB1, acc);
        f32x4 p;
        p[0] = __builtin_exp2f(acc[0] * SC2) * inv1;
        p[1] = __builtin_exp2f(acc[1] * SC2) * inv1;
        p[2] = __builtin_exp2f(acc[2] * SC2) * inv1;
        p[3] = __builtin_exp2f(acc[3] * SC2) * inv1;
        *reinterpret_cast<f32x4*>(arow1 + ch*32 + s*16) = p;
        u16x4 pb;
        pb[0] = f2bf(p[0]); pb[1] = f2bf(p[1]); pb[2] = f2bf(p[2]); pb[3] = f2bf(p[3]);
        *(AS3 u16x4*)(PBw + cl*80 + s*32 + g*8) = pb;
      }
      const bf16x8 ap = *(const AS3 bf16x8*)(PBw + cl*80 + g*16);
      #pragma unroll
      for (int dt = 0; dt < 4; ++dt) {
        const bf16x8 bv = *(const AS3 bf16x8*)(vb + (dt*16 + cl)*64 + ((g ^ kvkey) << 4));
        accP[dt] = mfma16(ap, bv, accP[dt]);
      }
    }
  }
  #undef STAGE_K
  #undef STAGE_KV

  // t1 ctx write
  #pragma unroll
  for (int r = 0; r < 4; ++r) {
    const size_t row = (size_t)(b * S_LEN + q0 + 128 + w*16 + g*4 + r);
    #pragma unroll
    for (int dt = 0; dt < 4; ++dt)
      ctx[row * DM + h * KDIM + dt*16 + cl] = f2bf(accP[dt][r]);
  }
}

// ---------------------------------------------------------------------------
extern "C" void kernel_launch(void* const* d_in, const int* in_sizes, int n_in,
                              void* d_out, int out_size, void* d_ws, size_t ws_size,
                              hipStream_t stream)
{
  const float* q_in = (const float*)d_in[0];
  const float* k_in = (const float*)d_in[1];
  const float* v_in = (const float*)d_in[2];
  const float* Wq   = (const float*)d_in[3];
  const float* bq   = (const float*)d_in[4];
  const float* Wk   = (const float*)d_in[5];
  const float* bk   = (const float*)d_in[6];
  const float* Wv   = (const float*)d_in[7];
  const float* bv   = (const float*)d_in[8];
  const float* Wo   = (const float*)d_in[9];
  const float* bo   = (const float*)d_in[10];

  unsigned short* wqbf = (unsigned short*)d_ws;
  unsigned short* wkbf = wqbf + (size_t)DM*DM;
  unsigned short* wvbf = wkbf + (size_t)DM*DM;
  unsigned short* wobf = wvbf + (size_t)DM*DM;
  unsigned short* Qhp  = wobf + (size_t)DM*DM;    // [b,h,s,d]
  unsigned short* Khp  = Qhp  + (size_t)MTOK*DM;  // [b,h,s,d]
  unsigned short* Vtp  = Khp  + (size_t)MTOK*DM;  // [b,h,d,s]
  unsigned short* ctx  = Vtp  + (size_t)MTOK*DM;  // [b*s, h*d]

  float* out0 = (float*)d_out;
  float* attn = out0 + (size_t)MTOK*DM;

  CvtArgs ca;
  ca.src[0] = Wq; ca.dst[0] = wqbf; ca.n[0] = DM*DM;
  ca.src[1] = Wk; ca.dst[1] = wkbf; ca.n[1] = DM*DM;
  ca.src[2] = Wv; ca.dst[2] = wvbf; ca.n[2] = DM*DM;
  ca.src[3] = Wo; ca.dst[3] = wobf; ca.n[3] = DM*DM;
  cvt_f32_bf16<<<dim3(64, 4), 256, 0, stream>>>(ca);

  GemmCvtArgs gq;
  gq.A[0] = q_in; gq.W[0] = wqbf; gq.bias[0] = bq; gq.dst[0] = Qhp; gq.mode[0] = 0;
  gq.A[1] = k_in; gq.W[1] = wkbf; gq.bias[1] = bk; gq.dst[1] = Khp; gq.mode[1] = 0;
  gq.A[2] = v_in; gq.W[2] = wvbf; gq.bias[2] = bv; gq.dst[2] = Vtp; gq.mode[2] = 1;
  gemm_cvt<<<dim3(8, 32, 3), 256, 0, stream>>>(gq);

  attn_fused12<<<dim3(256), 512, 0, stream>>>(Qhp, Khp, Vtp, attn, ctx);

  gemm_pipe<<<dim3(8, 32), 256, 0, stream>>>(ctx, wobf, bo, out0);
}

// Round 18
// 268.095 us; speedup vs baseline: 1.1287x; 1.1287x over previous
//
#include <hip/hip_runtime.h>
#include <hip/hip_bf16.h>
#include <stdint.h>

#define S_LEN 2048
#define NB 2
#define NH 16
#define DM 1024
#define KDIM 64
#define MTOK (NB*S_LEN)   // 4096 tokens

typedef __attribute__((ext_vector_type(8))) short bf16x8;
typedef __attribute__((ext_vector_type(4))) float f32x4;
typedef __attribute__((ext_vector_type(4))) unsigned short u16x4;
typedef __attribute__((ext_vector_type(8))) unsigned short u16x8;

#define AS1 __attribute__((address_space(1)))
#define AS3 __attribute__((address_space(3)))

__device__ __forceinline__ unsigned short f2bf(float f) {
  unsigned int u = __builtin_bit_cast(unsigned int, f);
  return (unsigned short)((u + 0x7fffu + ((u >> 16) & 1u)) >> 16);   // RNE
}
__device__ __forceinline__ f32x4 mfma16(bf16x8 a, bf16x8 b, f32x4 c) {
  return __builtin_amdgcn_mfma_f32_16x16x32_bf16(a, b, c, 0, 0, 0);
}

// ---------------------------------------------------------------------------
// fp32 -> bf16 convert: only the 4 weight matrices
// ---------------------------------------------------------------------------
struct CvtArgs {
  const float* src[4];
  unsigned short* dst[4];
  int n[4];
};

__global__ __launch_bounds__(256) void cvt_f32_bf16(CvtArgs a) {
  const int seg = blockIdx.y;
  const float* __restrict__ s = a.src[seg];
  unsigned short* __restrict__ d = a.dst[seg];
  const int n4 = a.n[seg] >> 2;
  const int stride = gridDim.x * blockDim.x;
  for (int i = blockIdx.x * blockDim.x + threadIdx.x; i < n4; i += stride) {
    const float4 v = reinterpret_cast<const float4*>(s)[i];
    u16x4 o;
    o[0] = f2bf(v.x); o[1] = f2bf(v.y); o[2] = f2bf(v.z); o[3] = f2bf(v.w);
    reinterpret_cast<u16x4*>(d)[i] = o;
  }
}

// ---------------------------------------------------------------------------
// gemm_cvt v2 (R16-proven): QKV projections with fused fp32->bf16 A-convert,
// counted-vmcnt ledger.
// ---------------------------------------------------------------------------
struct GemmCvtArgs {
  const float* A[3];
  const unsigned short* W[3];
  const float* bias[3];
  void* dst[3];
  int mode[3];
};

__global__ __launch_bounds__(256, 2)
void gemm_cvt(GemmCvtArgs ga)
{
  __shared__ __align__(16) char smem[32768];   // 2 x (A 8K + B 8K); Cs union

  const int z = blockIdx.z;
  const float* __restrict__ Af = ga.A[z];
  const unsigned short* __restrict__ Bw = ga.W[z];
  const float* __restrict__ bias = ga.bias[z];
  void* __restrict__ dst = ga.dst[z];
  const int mode = ga.mode[z];

  const int t = threadIdx.x;
  const int w = t >> 6, l = t & 63;
  const int g = l >> 4, cl = l & 15;

  const int L   = blockIdx.x + 8 * blockIdx.y;   // 0..255
  const int xcd = L & 7, ix = L >> 3;
  const int m0  = (xcd * 4 + (ix & 3)) * 128;
  const int n0  = (ix >> 2) * 128;

  const float* Ap = Af + (size_t)(m0 + (t >> 2)) * DM + (t & 3) * 8;
  const unsigned short* Bg = Bw + (size_t)(n0 + (t >> 2)) * DM + (t & 3) * 8;

  const int wm = (w >> 1) * 64, wn = (w & 1) * 64;

  f32x4 acc[4][4];
  #pragma unroll
  for (int i = 0; i < 4; ++i)
    #pragma unroll
    for (int j = 0; j < 4; ++j) acc[i][j] = 0.f;

  #define STAGE_B(step) do {                                                        \
    AS3 char* _buf = (AS3 char*)smem + ((step) & 1) * 16384;                         \
    __builtin_amdgcn_global_load_lds((const AS1 void*)(Bg + (step)*32),              \
                                     (AS3 void*)(_buf + 8192 + w*1024),   16, 0, 0); \
    __builtin_amdgcn_global_load_lds((const AS1 void*)(Bg + (step)*32 + 64*DM),      \
                                     (AS3 void*)(_buf + 12288 + w*1024),  16, 0, 0); \
  } while (0)

  #define ALOAD(step, ra, rb, rc, rd) do {                                           \
    const float* _p = Ap + (step) * 32;                                              \
    ra = *reinterpret_cast<const float4*>(_p);                                       \
    rb = *reinterpret_cast<const float4*>(_p + 4);                                   \
    const float* _q = _p + (size_t)64 * DM;                                          \
    rc = *reinterpret_cast<const float4*>(_q);                                       \
    rd = *reinterpret_cast<const float4*>(_q + 4);                                   \
  } while (0)

  #define AWRITE(step, ra, rb, rc, rd) do {                                          \
    AS3 char* _buf = (AS3 char*)smem + ((step) & 1) * 16384;                         \
    u16x8 _w0, _w1;                                                                  \
    _w0[0]=f2bf(ra.x); _w0[1]=f2bf(ra.y); _w0[2]=f2bf(ra.z); _w0[3]=f2bf(ra.w);      \
    _w0[4]=f2bf(rb.x); _w0[5]=f2bf(rb.y); _w0[6]=f2bf(rb.z); _w0[7]=f2bf(rb.w);      \
    _w1[0]=f2bf(rc.x); _w1[1]=f2bf(rc.y); _w1[2]=f2bf(rc.z); _w1[3]=f2bf(rc.w);      \
    _w1[4]=f2bf(rd.x); _w1[5]=f2bf(rd.y); _w1[6]=f2bf(rd.z); _w1[7]=f2bf(rd.w);      \
    *(AS3 u16x8*)(_buf + t*16) = _w0;                                                \
    *(AS3 u16x8*)(_buf + 4096 + t*16) = _w1;                                         \
  } while (0)

  #define COMPUTE(s) do {                                                            \
    const AS3 unsigned short* bufA =                                                 \
        (const AS3 unsigned short*)((AS3 char*)smem + ((s) & 1) * 16384);            \
    const AS3 unsigned short* bufB = bufA + 4096;                                    \
    bf16x8 af[4], bfv[4];                                                            \
    _Pragma("unroll")                                                                \
    for (int i = 0; i < 4; ++i)                                                      \
      af[i] = *(const AS3 bf16x8*)(bufA + (wm + 16*i + cl) * 32 + g*8);              \
    _Pragma("unroll")                                                                \
    for (int j = 0; j < 4; ++j)                                                      \
      bfv[j] = *(const AS3 bf16x8*)(bufB + (wn + 16*j + cl) * 32 + g*8);             \
    _Pragma("unroll")                                                                \
    for (int i = 0; i < 4; ++i)                                                      \
      _Pragma("unroll")                                                              \
      for (int j = 0; j < 4; ++j)                                                    \
        acc[i][j] = mfma16(af[i], bfv[j], acc[i][j]);                                \
  } while (0)

  #define GSEC(s, c0,c1,c2,c3, n0_,n1_,n2_,n3_) do {                                 \
    asm volatile("s_waitcnt lgkmcnt(0)" ::: "memory");                               \
    asm volatile("s_waitcnt vmcnt(4)" ::: "memory");   /* B(s) landed */             \
    __builtin_amdgcn_s_barrier();                                                    \
    __builtin_amdgcn_sched_barrier(0);                                               \
    STAGE_B((s) + 1);                                                                \
    COMPUTE(s);                                                                      \
    asm volatile("s_waitcnt vmcnt(2)" ::: "memory");   /* A(s+1) landed */           \
    AWRITE((s) + 1, c0, c1, c2, c3);                                                 \
    if ((s) + 2 < 32) ALOAD((s) + 2, n0_, n1_, n2_, n3_);                            \
  } while (0)

  float4 e0, e1, e2, e3, o0, o1, o2, o3;
  STAGE_B(0);
  ALOAD(0, e0, e1, e2, e3);
  ALOAD(1, o0, o1, o2, o3);
  asm volatile("s_waitcnt vmcnt(4)" ::: "memory");   // B(0) + A(0) landed
  AWRITE(0, e0, e1, e2, e3);

  for (int sp = 0; sp < 15; ++sp) {
    GSEC(2*sp,     o0, o1, o2, o3,  e0, e1, e2, e3);
    GSEC(2*sp + 1, e0, e1, e2, e3,  o0, o1, o2, o3);
  }
  GSEC(30, o0, o1, o2, o3,  e0, e1, e2, e3);
  asm volatile("s_waitcnt lgkmcnt(0)" ::: "memory");
  asm volatile("s_waitcnt vmcnt(0)" ::: "memory");
  __builtin_amdgcn_s_barrier();
  __builtin_amdgcn_sched_barrier(0);
  COMPUTE(31);
  #undef GSEC
  #undef COMPUTE
  #undef AWRITE
  #undef ALOAD
  #undef STAGE_B

  if (mode == 1) {
    unsigned short* Cs = (unsigned short*)smem;
    __syncthreads();
    #pragma unroll
    for (int i = 0; i < 4; ++i) {
      #pragma unroll
      for (int j = 0; j < 4; ++j) {
        const int n = wn + 16*j + cl;
        const float bn = bias[n0 + n];
        const int u = (wm >> 2) + 4*i + g;
        const int us = u ^ (n & 31);
        u16x4 o;
        #pragma unroll
        for (int r = 0; r < 4; ++r) o[r] = f2bf(acc[i][j][r] + bn);
        *reinterpret_cast<u16x4*>(&Cs[n*128 + us*4]) = o;
      }
    }
    __syncthreads();
    {
      const int n = t >> 1, mh = (t & 1) * 64;
      const int ncol = n0 + n;
      const int h = ncol >> 6, d = ncol & (KDIM-1);
      const int b = m0 >> 11, s0 = m0 & (S_LEN-1);
      unsigned short* drow = (unsigned short*)dst
          + ((size_t)(b*NH + h)*KDIM + d)*S_LEN + s0 + mh;
      #pragma unroll
      for (int mm = 0; mm < 4; ++mm) {
        u16x4 v[4];
        #pragma unroll
        for (int k = 0; k < 4; ++k) {
          const int us = ((mh >> 2) + mm*4 + k) ^ (n & 31);
          v[k] = *reinterpret_cast<const u16x4*>(&Cs[n*128 + us*4]);
        }
        u16x8 w01, w23;
        #pragma unroll
        for (int e = 0; e < 4; ++e) {
          w01[e] = v[0][e]; w01[4+e] = v[1][e];
          w23[e] = v[2][e]; w23[4+e] = v[3][e];
        }
        *reinterpret_cast<u16x8*>(drow + mm*16)     = w01;
        *reinterpret_cast<u16x8*>(drow + mm*16 + 8) = w23;
      }
    }
  } else {
    #pragma unroll
    for (int i = 0; i < 4; ++i)
      #pragma unroll
      for (int j = 0; j < 4; ++j) {
        const int ncol = n0 + wn + 16*j + cl;
        const float bn = bias[ncol];
        #pragma unroll
        for (int r = 0; r < 4; ++r) {
          const int m = m0 + wm + 16*i + g*4 + r;
          const float v = acc[i][j][r] + bn;
          const int b = m >> 11, sR = m & (S_LEN-1);
          const int h = ncol >> 6, d = ncol & (KDIM-1);
          ((unsigned short*)dst)[((size_t)(b*NH + h)*S_LEN + sR)*KDIM + d] = f2bf(v);
        }
      }
  }
}

// ---------------------------------------------------------------------------
// Pipelined GEMM (R9-proven) for the out-projection.
// ---------------------------------------------------------------------------
__global__ __launch_bounds__(256, 2)
void gemm_pipe(const unsigned short* __restrict__ A,
               const unsigned short* __restrict__ Bw,
               const float* __restrict__ bias,
               float* __restrict__ dst)
{
  __shared__ __align__(16) char smem[32768];

  const int t = threadIdx.x;
  const int w = t >> 6, l = t & 63;
  const int g = l >> 4, cl = l & 15;

  const int L   = blockIdx.x + 8 * blockIdx.y;   // 0..255
  const int xcd = L & 7, ix = L >> 3;
  const int m0  = (xcd * 4 + (ix & 3)) * 128;
  const int n0  = (ix >> 2) * 128;

  const unsigned short* Ag = A  + (size_t)(m0 + (t >> 2)) * DM + (t & 3) * 8;
  const unsigned short* Bg = Bw + (size_t)(n0 + (t >> 2)) * DM + (t & 3) * 8;

  const int wm = (w >> 1) * 64, wn = (w & 1) * 64;

  f32x4 acc[4][4];
  #pragma unroll
  for (int i = 0; i < 4; ++i)
    #pragma unroll
    for (int j = 0; j < 4; ++j) acc[i][j] = 0.f;

  #define STAGE(step) do {                                                          \
    AS3 char* _buf = (AS3 char*)smem + ((step) & 1) * 16384;                         \
    __builtin_amdgcn_global_load_lds((const AS1 void*)(Ag + (step)*32),              \
                                     (AS3 void*)(_buf + w*1024),          16, 0, 0); \
    __builtin_amdgcn_global_load_lds((const AS1 void*)(Ag + (step)*32 + 64*DM),      \
                                     (AS3 void*)(_buf + 4096 + w*1024),   16, 0, 0); \
    __builtin_amdgcn_global_load_lds((const AS1 void*)(Bg + (step)*32),              \
                                     (AS3 void*)(_buf + 8192 + w*1024),   16, 0, 0); \
    __builtin_amdgcn_global_load_lds((const AS1 void*)(Bg + (step)*32 + 64*DM),      \
                                     (AS3 void*)(_buf + 12288 + w*1024),  16, 0, 0); \
  } while (0)

  STAGE(0);
  for (int s = 0; s < 32; ++s) {
    if (s < 31) {
      STAGE(s + 1);
      asm volatile("s_waitcnt vmcnt(4)" ::: "memory");
    } else {
      asm volatile("s_waitcnt vmcnt(0)" ::: "memory");
    }
    __builtin_amdgcn_s_barrier();
    __builtin_amdgcn_sched_barrier(0);

    const AS3 unsigned short* bufA =
        (const AS3 unsigned short*)((AS3 char*)smem + (s & 1) * 16384);
    const AS3 unsigned short* bufB = bufA + 4096;
    bf16x8 af[4], bfv[4];
    #pragma unroll
    for (int i = 0; i < 4; ++i)
      af[i] = *(const AS3 bf16x8*)(bufA + (wm + 16*i + cl) * 32 + g*8);
    #pragma unroll
    for (int j = 0; j < 4; ++j)
      bfv[j] = *(const AS3 bf16x8*)(bufB + (wn + 16*j + cl) * 32 + g*8);
    #pragma unroll
    for (int i = 0; i < 4; ++i)
      #pragma unroll
      for (int j = 0; j < 4; ++j)
        acc[i][j] = mfma16(af[i], bfv[j], acc[i][j]);

    __builtin_amdgcn_sched_barrier(0);
    __builtin_amdgcn_s_barrier();
  }
  #undef STAGE

  #pragma unroll
  for (int i = 0; i < 4; ++i)
    #pragma unroll
    for (int j = 0; j < 4; ++j) {
      const int ncol = n0 + wn + 16*j + cl;
      const float bn = bias[ncol];
      #pragma unroll
      for (int r = 0; r < 4; ++r) {
        const int m = m0 + wm + 16*i + g*4 + r;
        dst[(size_t)m * DM + ncol] = acc[i][j][r] + bn;
      }
    }
}

// ---------------------------------------------------------------------------
// Fused attention v13: R16's attn_fused10 with pass A coarsened to 16
// sections x 4 chunks over a 16-slot K ring (64 KB = KB+VB space), staged by
// waves 0-3 (4 loads/wave/section), steady vmcnt(4) = one full section of
// slack (R14-proven ratio). Waves 4-7 remain wait-free in pass A.
// Pass B byte-identical to R14/R16: 32 sections, vmcnt(16) steady.
// ---------------------------------------------------------------------------
__global__ __launch_bounds__(512, 4)
void attn_fused13(const unsigned short* __restrict__ Qh,
                  const unsigned short* __restrict__ Kh,
                  const unsigned short* __restrict__ Vt,
                  float* __restrict__ attn,
                  unsigned short* __restrict__ ctx)
{
  __shared__ __align__(16) char smem[75776];
  AS3 char* const KB = (AS3 char*)smem;        // pass A: 16 slots; pass B: 8 slots
  AS3 char* const VB = (AS3 char*)smem + 32768;

  const int id  = blockIdx.x;                 // 512 = 8 XCD x 64
  const int swz = (id & 7) * 64 + (id >> 3);  // bijective XCD swizzle
  const int bh  = swz >> 4;                   // head 0..31
  const int q0  = (swz & 15) * 128;           // 128-row q tile

  const int t = threadIdx.x, w = t >> 6, l = t & 63;
  const int g = l >> 4, cl = l & 15;
  AS3 char* const PBw = (AS3 char*)smem + 65536 + w * 1280;
  const int b = bh >> 4, h = bh & 15;

  const unsigned short* Qb = Qh + ((size_t)bh * S_LEN + q0 + w*16 + cl) * KDIM;
  const bf16x8 qf0 = *reinterpret_cast<const bf16x8*>(Qb + g*8);
  const bf16x8 qf1 = *reinterpret_cast<const bf16x8*>(Qb + 32 + g*8);

  const int rs = (w & 3)*8 + (l >> 3), js = l & 7;
  const unsigned short* pK = Kh + (size_t)bh*S_LEN*KDIM + (size_t)rs*KDIM
                                + (size_t)((js ^ (rs & 7)) * 8);
  const int dsv = (w & 3)*16 + (l >> 2), jv = l & 3;
  const int kst = (dsv & 3) ^ ((dsv >> 2) & 3);
  const unsigned short* pV = Vt + (size_t)bh*KDIM*S_LEN + (size_t)dsv*S_LEN
                                + (size_t)((jv ^ kst) * 8);

  const unsigned kvkey = (unsigned)((cl & 3) ^ ((cl >> 2) & 3));
  const unsigned koff0 = (unsigned)(cl*128 + ((g ^ (cl & 7)) << 4));
  const unsigned koff1 = (unsigned)(cl*128 + (((g + 4) ^ (cl & 7)) << 4));
  const float SC2 = 0.125f * 1.44269504f;     // 1/sqrt(64) * log2(e)

  // pass A: 16-slot ring, staged by waves 0-3 (guarded past chunk 63)
  #define STAGE_A(ch) do { if ((w < 4) && ((ch) < 64))                                      \
      __builtin_amdgcn_global_load_lds((const AS1 void*)(pK + (size_t)(ch)*2048),           \
          (AS3 void*)(KB + ((ch) & 15)*4096 + (w&3)*1024), 16, 0, 0); } while (0)
  // pass B staging (R14): K by waves 0-3, V by waves 4-7, 8-slot rings
  #define STAGE_KV(ch) do { int _b = (ch) & 7;                                              \
    if (w < 4) __builtin_amdgcn_global_load_lds((const AS1 void*)(pK + (size_t)(ch)*2048),  \
                   (AS3 void*)(KB + _b*4096 + (w&3)*1024), 16, 0, 0);                       \
    else       __builtin_amdgcn_global_load_lds((const AS1 void*)(pV + (size_t)(ch)*32),    \
                   (AS3 void*)(VB + _b*4096 + (w&3)*1024), 16, 0, 0); } while (0)

  // ================= PASS A: lean row sums, 16 sections x 128 kv ===========
  float sa0 = 0.f, sa1 = 0.f, sa2 = 0.f, sa3 = 0.f;

  for (int i = 0; i < 8; ++i) STAGE_A(i);
  for (int k = 0; k < 16; ++k) {
    const int c = 4 * k;
    if (w < 4) {
      if (k < 15) asm volatile("s_waitcnt vmcnt(4)" ::: "memory");  // c..c+3 landed
      else        asm volatile("s_waitcnt vmcnt(0)" ::: "memory");  // last 4 chunks
    }
    __builtin_amdgcn_s_barrier();
    __builtin_amdgcn_sched_barrier(0);
    STAGE_A(c + 8); STAGE_A(c + 9); STAGE_A(c + 10); STAGE_A(c + 11);
    #pragma unroll
    for (int cc = 0; cc < 4; ++cc) {
      AS3 const char* kb = KB + ((c + cc) & 15) * 4096;
      #pragma unroll
      for (int s = 0; s < 2; ++s) {
        const bf16x8 k0 = *(const AS3 bf16x8*)(kb + s*2048 + koff0);
        const bf16x8 k1 = *(const AS3 bf16x8*)(kb + s*2048 + koff1);
        f32x4 acc = {0.f, 0.f, 0.f, 0.f};
        acc = mfma16(k0, qf0, acc);
        acc = mfma16(k1, qf1, acc);
        sa0 += __builtin_exp2f(acc[0] * SC2);
        sa1 += __builtin_exp2f(acc[1] * SC2);
        sa2 += __builtin_exp2f(acc[2] * SC2);
        sa3 += __builtin_exp2f(acc[3] * SC2);
      }
    }
  }

  float ssum = (sa0 + sa1) + (sa2 + sa3);
  ssum += __shfl_xor(ssum, 16, 64);
  ssum += __shfl_xor(ssum, 32, 64);
  const float inv = 1.0f / ssum;                 // row q = w*16 + cl

  __syncthreads();                               // drain pass A fully

  // ================= PASS B: store + PV + ctx, 32 sections (R14) ===========
  float* const arow = attn + ((size_t)bh * S_LEN + q0 + w*16 + cl) * S_LEN + g*4;
  f32x4 accP[4];
  #pragma unroll
  for (int dt = 0; dt < 4; ++dt) accP[dt] = 0.f;

  for (int i = 0; i < 6; ++i) STAGE_KV(i);
  for (int k = 0; k < 32; ++k) {
    const int c = 2 * k;
    if (k < 3) asm volatile("s_waitcnt vmcnt(4)"  ::: "memory");
    else       asm volatile("s_waitcnt vmcnt(16)" ::: "memory");  // 4 loads + 12-store slack
    __builtin_amdgcn_s_barrier();
    __builtin_amdgcn_sched_barrier(0);
    STAGE_KV(c + 6);
    STAGE_KV(c + 7);
    #pragma unroll
    for (int cc = 0; cc < 2; ++cc) {
      const int ch = c + cc;
      AS3 const char* kb = KB + (ch & 7) * 4096;
      AS3 const char* vb = VB + (ch & 7) * 4096;
      #pragma unroll
      for (int s = 0; s < 2; ++s) {
        const bf16x8 k0 = *(const AS3 bf16x8*)(kb + s*2048 + koff0);
        const bf16x8 k1 = *(const AS3 bf16x8*)(kb + s*2048 + koff1);
        f32x4 acc = {0.f, 0.f, 0.f, 0.f};
        acc = mfma16(k0, qf0, acc);
        acc = mfma16(k1, qf1, acc);
        f32x4 p;
        p[0] = __builtin_exp2f(acc[0] * SC2) * inv;
        p[1] = __builtin_exp2f(acc[1] * SC2) * inv;
        p[2] = __builtin_exp2f(acc[2] * SC2) * inv;
        p[3] = __builtin_exp2f(acc[3] * SC2) * inv;
        *reinterpret_cast<f32x4*>(arow + ch*32 + s*16) = p;   // streamed fp32 attn
        u16x4 pb;
        pb[0] = f2bf(p[0]); pb[1] = f2bf(p[1]); pb[2] = f2bf(p[2]); pb[3] = f2bf(p[3]);
        *(AS3 u16x4*)(PBw + cl*80 + s*32 + g*8) = pb;
      }
      const bf16x8 ap = *(const AS3 bf16x8*)(PBw + cl*80 + g*16);
      #pragma unroll
      for (int dt = 0; dt < 4; ++dt) {
        const bf16x8 bv = *(const AS3 bf16x8*)(vb + (dt*16 + cl)*64 + ((g ^ kvkey) << 4));
        accP[dt] = mfma16(ap, bv, accP[dt]);     // P pre-normalized
      }
    }
  }
  #undef STAGE_A
  #undef STAGE_KV

  // ctx write: lane holds O[q = g*4+r][d = dt*16+cl] (already normalized)
  #pragma unroll
  for (int r = 0; r < 4; ++r) {
    const size_t row = (size_t)(b * S_LEN + q0 + w*16 + g*4 + r);
    #pragma unroll
    for (int dt = 0; dt < 4; ++dt)
      ctx[row * DM + h * KDIM + dt*16 + cl] = f2bf(accP[dt][r]);
  }
}

// ---------------------------------------------------------------------------
extern "C" void kernel_launch(void* const* d_in, const int* in_sizes, int n_in,
                              void* d_out, int out_size, void* d_ws, size_t ws_size,
                              hipStream_t stream)
{
  const float* q_in = (const float*)d_in[0];
  const float* k_in = (const float*)d_in[1];
  const float* v_in = (const float*)d_in[2];
  const float* Wq   = (const float*)d_in[3];
  const float* bq   = (const float*)d_in[4];
  const float* Wk   = (const float*)d_in[5];
  const float* bk   = (const float*)d_in[6];
  const float* Wv   = (const float*)d_in[7];
  const float* bv   = (const float*)d_in[8];
  const float* Wo   = (const float*)d_in[9];
  const float* bo   = (const float*)d_in[10];

  unsigned short* wqbf = (unsigned short*)d_ws;
  unsigned short* wkbf = wqbf + (size_t)DM*DM;
  unsigned short* wvbf = wkbf + (size_t)DM*DM;
  unsigned short* wobf = wvbf + (size_t)DM*DM;
  unsigned short* Qhp  = wobf + (size_t)DM*DM;    // [b,h,s,d]
  unsigned short* Khp  = Qhp  + (size_t)MTOK*DM;  // [b,h,s,d]
  unsigned short* Vtp  = Khp  + (size_t)MTOK*DM;  // [b,h,d,s]
  unsigned short* ctx  = Vtp  + (size_t)MTOK*DM;  // [b*s, h*d]

  float* out0 = (float*)d_out;
  float* attn = out0 + (size_t)MTOK*DM;

  CvtArgs ca;
  ca.src[0] = Wq; ca.dst[0] = wqbf; ca.n[0] = DM*DM;
  ca.src[1] = Wk; ca.dst[1] = wkbf; ca.n[1] = DM*DM;
  ca.src[2] = Wv; ca.dst[2] = wvbf; ca.n[2] = DM*DM;
  ca.src[3] = Wo; ca.dst[3] = wobf; ca.n[3] = DM*DM;
  cvt_f32_bf16<<<dim3(64, 4), 256, 0, stream>>>(ca);

  GemmCvtArgs gq;
  gq.A[0] = q_in; gq.W[0] = wqbf; gq.bias[0] = bq; gq.dst[0] = Qhp; gq.mode[0] = 0;
  gq.A[1] = k_in; gq.W[1] = wkbf; gq.bias[1] = bk; gq.dst[1] = Khp; gq.mode[1] = 0;
  gq.A[2] = v_in; gq.W[2] = wvbf; gq.bias[2] = bv; gq.dst[2] = Vtp; gq.mode[2] = 1;
  gemm_cvt<<<dim3(8, 32, 3), 256, 0, stream>>>(gq);

  attn_fused13<<<dim3(512), 512, 0, stream>>>(Qhp, Khp, Vtp, attn, ctx);

  gemm_pipe<<<dim3(8, 32), 256, 0, stream>>>(ctx, wobf, bo, out0);
}

// Round 19
// 265.178 us; speedup vs baseline: 1.1411x; 1.0110x over previous
//
#include <hip/hip_runtime.h>
#include <hip/hip_bf16.h>
#include <stdint.h>

#define S_LEN 2048
#define NB 2
#define NH 16
#define DM 1024
#define KDIM 64
#define MTOK (NB*S_LEN)   // 4096 tokens

typedef __attribute__((ext_vector_type(8))) short bf16x8;
typedef __attribute__((ext_vector_type(4))) float f32x4;
typedef __attribute__((ext_vector_type(4))) unsigned short u16x4;
typedef __attribute__((ext_vector_type(8))) unsigned short u16x8;

#define AS1 __attribute__((address_space(1)))
#define AS3 __attribute__((address_space(3)))

__device__ __forceinline__ unsigned short f2bf(float f) {
  unsigned int u = __builtin_bit_cast(unsigned int, f);
  return (unsigned short)((u + 0x7fffu + ((u >> 16) & 1u)) >> 16);   // RNE
}
__device__ __forceinline__ f32x4 mfma16(bf16x8 a, bf16x8 b, f32x4 c) {
  return __builtin_amdgcn_mfma_f32_16x16x32_bf16(a, b, c, 0, 0, 0);
}

// ---------------------------------------------------------------------------
// fp32 -> bf16 convert: only the 4 weight matrices
// ---------------------------------------------------------------------------
struct CvtArgs {
  const float* src[4];
  unsigned short* dst[4];
  int n[4];
};

__global__ __launch_bounds__(256) void cvt_f32_bf16(CvtArgs a) {
  const int seg = blockIdx.y;
  const float* __restrict__ s = a.src[seg];
  unsigned short* __restrict__ d = a.dst[seg];
  const int n4 = a.n[seg] >> 2;
  const int stride = gridDim.x * blockDim.x;
  for (int i = blockIdx.x * blockDim.x + threadIdx.x; i < n4; i += stride) {
    const float4 v = reinterpret_cast<const float4*>(s)[i];
    u16x4 o;
    o[0] = f2bf(v.x); o[1] = f2bf(v.y); o[2] = f2bf(v.z); o[3] = f2bf(v.w);
    reinterpret_cast<u16x4*>(d)[i] = o;
  }
}

// ---------------------------------------------------------------------------
// gemm_cvt v2 (R16-proven): QKV projections with fused fp32->bf16 A-convert,
// counted-vmcnt ledger (no full drains in the steady loop).
// ---------------------------------------------------------------------------
struct GemmCvtArgs {
  const float* A[3];
  const unsigned short* W[3];
  const float* bias[3];
  void* dst[3];
  int mode[3];
};

__global__ __launch_bounds__(256, 2)
void gemm_cvt(GemmCvtArgs ga)
{
  __shared__ __align__(16) char smem[32768];   // 2 x (A 8K + B 8K); Cs union

  const int z = blockIdx.z;
  const float* __restrict__ Af = ga.A[z];
  const unsigned short* __restrict__ Bw = ga.W[z];
  const float* __restrict__ bias = ga.bias[z];
  void* __restrict__ dst = ga.dst[z];
  const int mode = ga.mode[z];

  const int t = threadIdx.x;
  const int w = t >> 6, l = t & 63;
  const int g = l >> 4, cl = l & 15;

  const int L   = blockIdx.x + 8 * blockIdx.y;   // 0..255
  const int xcd = L & 7, ix = L >> 3;
  const int m0  = (xcd * 4 + (ix & 3)) * 128;
  const int n0  = (ix >> 2) * 128;

  const float* Ap = Af + (size_t)(m0 + (t >> 2)) * DM + (t & 3) * 8;
  const unsigned short* Bg = Bw + (size_t)(n0 + (t >> 2)) * DM + (t & 3) * 8;

  const int wm = (w >> 1) * 64, wn = (w & 1) * 64;

  f32x4 acc[4][4];
  #pragma unroll
  for (int i = 0; i < 4; ++i)
    #pragma unroll
    for (int j = 0; j < 4; ++j) acc[i][j] = 0.f;

  #define STAGE_B(step) do {                                                        \
    AS3 char* _buf = (AS3 char*)smem + ((step) & 1) * 16384;                         \
    __builtin_amdgcn_global_load_lds((const AS1 void*)(Bg + (step)*32),              \
                                     (AS3 void*)(_buf + 8192 + w*1024),   16, 0, 0); \
    __builtin_amdgcn_global_load_lds((const AS1 void*)(Bg + (step)*32 + 64*DM),      \
                                     (AS3 void*)(_buf + 12288 + w*1024),  16, 0, 0); \
  } while (0)

  #define ALOAD(step, ra, rb, rc, rd) do {                                           \
    const float* _p = Ap + (step) * 32;                                              \
    ra = *reinterpret_cast<const float4*>(_p);                                       \
    rb = *reinterpret_cast<const float4*>(_p + 4);                                   \
    const float* _q = _p + (size_t)64 * DM;                                          \
    rc = *reinterpret_cast<const float4*>(_q);                                       \
    rd = *reinterpret_cast<const float4*>(_q + 4);                                   \
  } while (0)

  #define AWRITE(step, ra, rb, rc, rd) do {                                          \
    AS3 char* _buf = (AS3 char*)smem + ((step) & 1) * 16384;                         \
    u16x8 _w0, _w1;                                                                  \
    _w0[0]=f2bf(ra.x); _w0[1]=f2bf(ra.y); _w0[2]=f2bf(ra.z); _w0[3]=f2bf(ra.w);      \
    _w0[4]=f2bf(rb.x); _w0[5]=f2bf(rb.y); _w0[6]=f2bf(rb.z); _w0[7]=f2bf(rb.w);      \
    _w1[0]=f2bf(rc.x); _w1[1]=f2bf(rc.y); _w1[2]=f2bf(rc.z); _w1[3]=f2bf(rc.w);      \
    _w1[4]=f2bf(rd.x); _w1[5]=f2bf(rd.y); _w1[6]=f2bf(rd.z); _w1[7]=f2bf(rd.w);      \
    *(AS3 u16x8*)(_buf + t*16) = _w0;                                                \
    *(AS3 u16x8*)(_buf + 4096 + t*16) = _w1;                                         \
  } while (0)

  #define COMPUTE(s) do {                                                            \
    const AS3 unsigned short* bufA =                                                 \
        (const AS3 unsigned short*)((AS3 char*)smem + ((s) & 1) * 16384);            \
    const AS3 unsigned short* bufB = bufA + 4096;                                    \
    bf16x8 af[4], bfv[4];                                                            \
    _Pragma("unroll")                                                                \
    for (int i = 0; i < 4; ++i)                                                      \
      af[i] = *(const AS3 bf16x8*)(bufA + (wm + 16*i + cl) * 32 + g*8);              \
    _Pragma("unroll")                                                                \
    for (int j = 0; j < 4; ++j)                                                      \
      bfv[j] = *(const AS3 bf16x8*)(bufB + (wn + 16*j + cl) * 32 + g*8);             \
    _Pragma("unroll")                                                                \
    for (int i = 0; i < 4; ++i)                                                      \
      _Pragma("unroll")                                                              \
      for (int j = 0; j < 4; ++j)                                                    \
        acc[i][j] = mfma16(af[i], bfv[j], acc[i][j]);                                \
  } while (0)

  // steady-state section (s = 0..30):
  #define GSEC(s, c0,c1,c2,c3, n0_,n1_,n2_,n3_) do {                                 \
    asm volatile("s_waitcnt lgkmcnt(0)" ::: "memory");                               \
    asm volatile("s_waitcnt vmcnt(4)" ::: "memory");   /* B(s) landed */             \
    __builtin_amdgcn_s_barrier();                                                    \
    __builtin_amdgcn_sched_barrier(0);                                               \
    STAGE_B((s) + 1);                                                                \
    COMPUTE(s);                                                                      \
    asm volatile("s_waitcnt vmcnt(2)" ::: "memory");   /* A(s+1) landed */           \
    AWRITE((s) + 1, c0, c1, c2, c3);                                                 \
    if ((s) + 2 < 32) ALOAD((s) + 2, n0_, n1_, n2_, n3_);                            \
  } while (0)

  float4 e0, e1, e2, e3, o0, o1, o2, o3;
  STAGE_B(0);
  ALOAD(0, e0, e1, e2, e3);
  ALOAD(1, o0, o1, o2, o3);
  asm volatile("s_waitcnt vmcnt(4)" ::: "memory");   // B(0) + A(0) landed
  AWRITE(0, e0, e1, e2, e3);

  for (int sp = 0; sp < 15; ++sp) {
    GSEC(2*sp,     o0, o1, o2, o3,  e0, e1, e2, e3);
    GSEC(2*sp + 1, e0, e1, e2, e3,  o0, o1, o2, o3);
  }
  GSEC(30, o0, o1, o2, o3,  e0, e1, e2, e3);
  asm volatile("s_waitcnt lgkmcnt(0)" ::: "memory");
  asm volatile("s_waitcnt vmcnt(0)" ::: "memory");
  __builtin_amdgcn_s_barrier();
  __builtin_amdgcn_sched_barrier(0);
  COMPUTE(31);
  #undef GSEC
  #undef COMPUTE
  #undef AWRITE
  #undef ALOAD
  #undef STAGE_B

  if (mode == 1) {
    unsigned short* Cs = (unsigned short*)smem;
    __syncthreads();
    #pragma unroll
    for (int i = 0; i < 4; ++i) {
      #pragma unroll
      for (int j = 0; j < 4; ++j) {
        const int n = wn + 16*j + cl;
        const float bn = bias[n0 + n];
        const int u = (wm >> 2) + 4*i + g;
        const int us = u ^ (n & 31);
        u16x4 o;
        #pragma unroll
        for (int r = 0; r < 4; ++r) o[r] = f2bf(acc[i][j][r] + bn);
        *reinterpret_cast<u16x4*>(&Cs[n*128 + us*4]) = o;
      }
    }
    __syncthreads();
    {
      const int n = t >> 1, mh = (t & 1) * 64;
      const int ncol = n0 + n;
      const int h = ncol >> 6, d = ncol & (KDIM-1);
      const int b = m0 >> 11, s0 = m0 & (S_LEN-1);
      unsigned short* drow = (unsigned short*)dst
          + ((size_t)(b*NH + h)*KDIM + d)*S_LEN + s0 + mh;
      #pragma unroll
      for (int mm = 0; mm < 4; ++mm) {
        u16x4 v[4];
        #pragma unroll
        for (int k = 0; k < 4; ++k) {
          const int us = ((mh >> 2) + mm*4 + k) ^ (n & 31);
          v[k] = *reinterpret_cast<const u16x4*>(&Cs[n*128 + us*4]);
        }
        u16x8 w01, w23;
        #pragma unroll
        for (int e = 0; e < 4; ++e) {
          w01[e] = v[0][e]; w01[4+e] = v[1][e];
          w23[e] = v[2][e]; w23[4+e] = v[3][e];
        }
        *reinterpret_cast<u16x8*>(drow + mm*16)     = w01;
        *reinterpret_cast<u16x8*>(drow + mm*16 + 8) = w23;
      }
    }
  } else {
    #pragma unroll
    for (int i = 0; i < 4; ++i)
      #pragma unroll
      for (int j = 0; j < 4; ++j) {
        const int ncol = n0 + wn + 16*j + cl;
        const float bn = bias[ncol];
        #pragma unroll
        for (int r = 0; r < 4; ++r) {
          const int m = m0 + wm + 16*i + g*4 + r;
          const float v = acc[i][j][r] + bn;
          const int b = m >> 11, sR = m & (S_LEN-1);
          const int h = ncol >> 6, d = ncol & (KDIM-1);
          ((unsigned short*)dst)[((size_t)(b*NH + h)*S_LEN + sR)*KDIM + d] = f2bf(v);
        }
      }
  }
}

// ---------------------------------------------------------------------------
// Pipelined GEMM (R9-proven) for the out-projection (bf16 A = ctx).
// ---------------------------------------------------------------------------
__global__ __launch_bounds__(256, 2)
void gemm_pipe(const unsigned short* __restrict__ A,
               const unsigned short* __restrict__ Bw,
               const float* __restrict__ bias,
               float* __restrict__ dst)
{
  __shared__ __align__(16) char smem[32768];

  const int t = threadIdx.x;
  const int w = t >> 6, l = t & 63;
  const int g = l >> 4, cl = l & 15;

  const int L   = blockIdx.x + 8 * blockIdx.y;   // 0..255
  const int xcd = L & 7, ix = L >> 3;
  const int m0  = (xcd * 4 + (ix & 3)) * 128;
  const int n0  = (ix >> 2) * 128;

  const unsigned short* Ag = A  + (size_t)(m0 + (t >> 2)) * DM + (t & 3) * 8;
  const unsigned short* Bg = Bw + (size_t)(n0 + (t >> 2)) * DM + (t & 3) * 8;

  const int wm = (w >> 1) * 64, wn = (w & 1) * 64;

  f32x4 acc[4][4];
  #pragma unroll
  for (int i = 0; i < 4; ++i)
    #pragma unroll
    for (int j = 0; j < 4; ++j) acc[i][j] = 0.f;

  #define STAGE(step) do {                                                          \
    AS3 char* _buf = (AS3 char*)smem + ((step) & 1) * 16384;                         \
    __builtin_amdgcn_global_load_lds((const AS1 void*)(Ag + (step)*32),              \
                                     (AS3 void*)(_buf + w*1024),          16, 0, 0); \
    __builtin_amdgcn_global_load_lds((const AS1 void*)(Ag + (step)*32 + 64*DM),      \
                                     (AS3 void*)(_buf + 4096 + w*1024),   16, 0, 0); \
    __builtin_amdgcn_global_load_lds((const AS1 void*)(Bg + (step)*32),              \
                                     (AS3 void*)(_buf + 8192 + w*1024),   16, 0, 0); \
    __builtin_amdgcn_global_load_lds((const AS1 void*)(Bg + (step)*32 + 64*DM),      \
                                     (AS3 void*)(_buf + 12288 + w*1024),  16, 0, 0); \
  } while (0)

  STAGE(0);
  for (int s = 0; s < 32; ++s) {
    if (s < 31) {
      STAGE(s + 1);
      asm volatile("s_waitcnt vmcnt(4)" ::: "memory");
    } else {
      asm volatile("s_waitcnt vmcnt(0)" ::: "memory");
    }
    __builtin_amdgcn_s_barrier();
    __builtin_amdgcn_sched_barrier(0);

    const AS3 unsigned short* bufA =
        (const AS3 unsigned short*)((AS3 char*)smem + (s & 1) * 16384);
    const AS3 unsigned short* bufB = bufA + 4096;
    bf16x8 af[4], bfv[4];
    #pragma unroll
    for (int i = 0; i < 4; ++i)
      af[i] = *(const AS3 bf16x8*)(bufA + (wm + 16*i + cl) * 32 + g*8);
    #pragma unroll
    for (int j = 0; j < 4; ++j)
      bfv[j] = *(const AS3 bf16x8*)(bufB + (wn + 16*j + cl) * 32 + g*8);
    #pragma unroll
    for (int i = 0; i < 4; ++i)
      #pragma unroll
      for (int j = 0; j < 4; ++j)
        acc[i][j] = mfma16(af[i], bfv[j], acc[i][j]);

    __builtin_amdgcn_sched_barrier(0);
    __builtin_amdgcn_s_barrier();
  }
  #undef STAGE

  #pragma unroll
  for (int i = 0; i < 4; ++i)
    #pragma unroll
    for (int j = 0; j < 4; ++j) {
      const int ncol = n0 + wn + 16*j + cl;
      const float bn = bias[ncol];
      #pragma unroll
      for (int r = 0; r < 4; ++r) {
        const int m = m0 + wm + 16*i + g*4 + r;
        dst[(size_t)m * DM + ncol] = acc[i][j][r] + bn;
      }
    }
}

// ---------------------------------------------------------------------------
// Fused attention v10 (R14-proven, byte-identical): 2 chunks (64 kv) per
// barrier section. Pass A = lean sums (vmcnt(4), waves 4-7 wait-free);
// pass B = store+PV+ctx (vmcnt(16) steady = 4 loads + 12-store slack).
// ---------------------------------------------------------------------------
__global__ __launch_bounds__(512, 4)
void attn_fused10(const unsigned short* __restrict__ Qh,
                  const unsigned short* __restrict__ Kh,
                  const unsigned short* __restrict__ Vt,
                  float* __restrict__ attn,
                  unsigned short* __restrict__ ctx)
{
  __shared__ __align__(16) char smem[75776];
  AS3 char* const KB = (AS3 char*)smem;
  AS3 char* const VB = (AS3 char*)smem + 32768;

  const int id  = blockIdx.x;                 // 512 = 8 XCD x 64
  const int swz = (id & 7) * 64 + (id >> 3);  // bijective XCD swizzle
  const int bh  = swz >> 4;                   // head 0..31
  const int q0  = (swz & 15) * 128;           // 128-row q tile

  const int t = threadIdx.x, w = t >> 6, l = t & 63;
  const int g = l >> 4, cl = l & 15;
  AS3 char* const PBw = (AS3 char*)smem + 65536 + w * 1280;
  const int b = bh >> 4, h = bh & 15;

  const unsigned short* Qb = Qh + ((size_t)bh * S_LEN + q0 + w*16 + cl) * KDIM;
  const bf16x8 qf0 = *reinterpret_cast<const bf16x8*>(Qb + g*8);
  const bf16x8 qf1 = *reinterpret_cast<const bf16x8*>(Qb + 32 + g*8);

  const int rs = (w & 3)*8 + (l >> 3), js = l & 7;
  const unsigned short* pK = Kh + (size_t)bh*S_LEN*KDIM + (size_t)rs*KDIM
                                + (size_t)((js ^ (rs & 7)) * 8);
  const int dsv = (w & 3)*16 + (l >> 2), jv = l & 3;
  const int kst = (dsv & 3) ^ ((dsv >> 2) & 3);
  const unsigned short* pV = Vt + (size_t)bh*KDIM*S_LEN + (size_t)dsv*S_LEN
                                + (size_t)((jv ^ kst) * 8);

  const unsigned kvkey = (unsigned)((cl & 3) ^ ((cl >> 2) & 3));
  const unsigned koff0 = (unsigned)(cl*128 + ((g ^ (cl & 7)) << 4));
  const unsigned koff1 = (unsigned)(cl*128 + (((g + 4) ^ (cl & 7)) << 4));
  const float SC2 = 0.125f * 1.44269504f;     // 1/sqrt(64) * log2(e)

  #define STAGE_K(ch) do { int _b = (ch) & 7;                                               \
    if (w < 4) __builtin_amdgcn_global_load_lds((const AS1 void*)(pK + (size_t)(ch)*2048),  \
                   (AS3 void*)(KB + _b*4096 + (w&3)*1024), 16, 0, 0); } while (0)
  #define STAGE_KV(ch) do { int _b = (ch) & 7;                                              \
    if (w < 4) __builtin_amdgcn_global_load_lds((const AS1 void*)(pK + (size_t)(ch)*2048),  \
                   (AS3 void*)(KB + _b*4096 + (w&3)*1024), 16, 0, 0);                       \
    else       __builtin_amdgcn_global_load_lds((const AS1 void*)(pV + (size_t)(ch)*32),    \
                   (AS3 void*)(VB + _b*4096 + (w&3)*1024), 16, 0, 0); } while (0)

  // ================= PASS A: lean row sums, 32 sections x 64 kv ============
  float sa0 = 0.f, sa1 = 0.f, sa2 = 0.f, sa3 = 0.f;

  for (int i = 0; i < 6; ++i) STAGE_K(i);
  for (int k = 0; k < 32; ++k) {
    const int c = 2 * k;
    if (w < 4) asm volatile("s_waitcnt vmcnt(4)" ::: "memory");  // c, c+1 landed
    __builtin_amdgcn_s_barrier();
    __builtin_amdgcn_sched_barrier(0);
    STAGE_K(c + 6);
    STAGE_K(c + 7);
    #pragma unroll
    for (int cc = 0; cc < 2; ++cc) {
      AS3 const char* kb = KB + ((c + cc) & 7) * 4096;
      #pragma unroll
      for (int s = 0; s < 2; ++s) {
        const bf16x8 k0 = *(const AS3 bf16x8*)(kb + s*2048 + koff0);
        const bf16x8 k1 = *(const AS3 bf16x8*)(kb + s*2048 + koff1);
        f32x4 acc = {0.f, 0.f, 0.f, 0.f};
        acc = mfma16(k0, qf0, acc);
        acc = mfma16(k1, qf1, acc);
        sa0 += __builtin_exp2f(acc[0] * SC2);
        sa1 += __builtin_exp2f(acc[1] * SC2);
        sa2 += __builtin_exp2f(acc[2] * SC2);
        sa3 += __builtin_exp2f(acc[3] * SC2);
      }
    }
  }

  float ssum = (sa0 + sa1) + (sa2 + sa3);
  ssum += __shfl_xor(ssum, 16, 64);
  ssum += __shfl_xor(ssum, 32, 64);
  const float inv = 1.0f / ssum;                 // row q = w*16 + cl

  __syncthreads();                               // drain pass A fully

  // ================= PASS B: store + PV + ctx, 32 sections =================
  float* const arow = attn + ((size_t)bh * S_LEN + q0 + w*16 + cl) * S_LEN + g*4;
  f32x4 accP[4];
  #pragma unroll
  for (int dt = 0; dt < 4; ++dt) accP[dt] = 0.f;

  for (int i = 0; i < 6; ++i) STAGE_KV(i);
  for (int k = 0; k < 32; ++k) {
    const int c = 2 * k;
    if (k < 3) asm volatile("s_waitcnt vmcnt(4)"  ::: "memory");
    else       asm volatile("s_waitcnt vmcnt(16)" ::: "memory");  // 4 loads + 12-store slack
    __builtin_amdgcn_s_barrier();
    __builtin_amdgcn_sched_barrier(0);
    STAGE_KV(c + 6);
    STAGE_KV(c + 7);
    #pragma unroll
    for (int cc = 0; cc < 2; ++cc) {
      const int ch = c + cc;
      AS3 const char* kb = KB + (ch & 7) * 4096;
      AS3 const char* vb = VB + (ch & 7) * 4096;
      #pragma unroll
      for (int s = 0; s < 2; ++s) {
        const bf16x8 k0 = *(const AS3 bf16x8*)(kb + s*2048 + koff0);
        const bf16x8 k1 = *(const AS3 bf16x8*)(kb + s*2048 + koff1);
        f32x4 acc = {0.f, 0.f, 0.f, 0.f};
        acc = mfma16(k0, qf0, acc);
        acc = mfma16(k1, qf1, acc);
        f32x4 p;
        p[0] = __builtin_exp2f(acc[0] * SC2) * inv;
        p[1] = __builtin_exp2f(acc[1] * SC2) * inv;
        p[2] = __builtin_exp2f(acc[2] * SC2) * inv;
        p[3] = __builtin_exp2f(acc[3] * SC2) * inv;
        *reinterpret_cast<f32x4*>(arow + ch*32 + s*16) = p;   // streamed fp32 attn
        u16x4 pb;
        pb[0] = f2bf(p[0]); pb[1] = f2bf(p[1]); pb[2] = f2bf(p[2]); pb[3] = f2bf(p[3]);
        *(AS3 u16x4*)(PBw + cl*80 + s*32 + g*8) = pb;
      }
      const bf16x8 ap = *(const AS3 bf16x8*)(PBw + cl*80 + g*16);
      #pragma unroll
      for (int dt = 0; dt < 4; ++dt) {
        const bf16x8 bv = *(const AS3 bf16x8*)(vb + (dt*16 + cl)*64 + ((g ^ kvkey) << 4));
        accP[dt] = mfma16(ap, bv, accP[dt]);     // P pre-normalized
      }
    }
  }
  #undef STAGE_K
  #undef STAGE_KV

  // ctx write: lane holds O[q = g*4+r][d = dt*16+cl] (already normalized)
  #pragma unroll
  for (int r = 0; r < 4; ++r) {
    const size_t row = (size_t)(b * S_LEN + q0 + w*16 + g*4 + r);
    #pragma unroll
    for (int dt = 0; dt < 4; ++dt)
      ctx[row * DM + h * KDIM + dt*16 + cl] = f2bf(accP[dt][r]);
  }
}

// ---------------------------------------------------------------------------
extern "C" void kernel_launch(void* const* d_in, const int* in_sizes, int n_in,
                              void* d_out, int out_size, void* d_ws, size_t ws_size,
                              hipStream_t stream)
{
  const float* q_in = (const float*)d_in[0];
  const float* k_in = (const float*)d_in[1];
  const float* v_in = (const float*)d_in[2];
  const float* Wq   = (const float*)d_in[3];
  const float* bq   = (const float*)d_in[4];
  const float* Wk   = (const float*)d_in[5];
  const float* bk   = (const float*)d_in[6];
  const float* Wv   = (const float*)d_in[7];
  const float* bv   = (const float*)d_in[8];
  const float* Wo   = (const float*)d_in[9];
  const float* bo   = (const float*)d_in[10];

  unsigned short* wqbf = (unsigned short*)d_ws;
  unsigned short* wkbf = wqbf + (size_t)DM*DM;
  unsigned short* wvbf = wkbf + (size_t)DM*DM;
  unsigned short* wobf = wvbf + (size_t)DM*DM;
  unsigned short* Qhp  = wobf + (size_t)DM*DM;    // [b,h,s,d]
  unsigned short* Khp  = Qhp  + (size_t)MTOK*DM;  // [b,h,s,d]
  unsigned short* Vtp  = Khp  + (size_t)MTOK*DM;  // [b,h,d,s]
  unsigned short* ctx  = Vtp  + (size_t)MTOK*DM;  // [b*s, h*d]

  float* out0 = (float*)d_out;
  float* attn = out0 + (size_t)MTOK*DM;

  CvtArgs ca;
  ca.src[0] = Wq; ca.dst[0] = wqbf; ca.n[0] = DM*DM;
  ca.src[1] = Wk; ca.dst[1] = wkbf; ca.n[1] = DM*DM;
  ca.src[2] = Wv; ca.dst[2] = wvbf; ca.n[2] = DM*DM;
  ca.src[3] = Wo; ca.dst[3] = wobf; ca.n[3] = DM*DM;
  cvt_f32_bf16<<<dim3(64, 4), 256, 0, stream>>>(ca);

  GemmCvtArgs gq;
  gq.A[0] = q_in; gq.W[0] = wqbf; gq.bias[0] = bq; gq.dst[0] = Qhp; gq.mode[0] = 0;
  gq.A[1] = k_in; gq.W[1] = wkbf; gq.bias[1] = bk; gq.dst[1] = Khp; gq.mode[1] = 0;
  gq.A[2] = v_in; gq.W[2] = wvbf; gq.bias[2] = bv; gq.dst[2] = Vtp; gq.mode[2] = 1;
  gemm_cvt<<<dim3(8, 32, 3), 256, 0, stream>>>(gq);

  attn_fused10<<<dim3(512), 512, 0, stream>>>(Qhp, Khp, Vtp, attn, ctx);

  gemm_pipe<<<dim3(8, 32), 256, 0, stream>>>(ctx, wobf, bo, out0);
}